// Round 2
// baseline (782.647 us; speedup 1.0000x reference)
//
#include <hip/hip_runtime.h>
#include <hip/hip_bf16.h>

#define N_NODES 50000
#define N_EDGES 800000
#define D 128
#define D2 64  // packed-uint (2×bf16) per row

static constexpr float SLOPE = 11.0f / 48.0f;  // eval-mode RReLU mean slope

typedef __attribute__((ext_vector_type(8))) short bf16x8;
typedef __attribute__((ext_vector_type(4))) float f32x4;
typedef __attribute__((ext_vector_type(2))) unsigned int u32x2;
typedef __attribute__((ext_vector_type(4))) unsigned int u32x4;

__device__ __forceinline__ float bf_lo(unsigned int v) { return __uint_as_float(v << 16); }
__device__ __forceinline__ float bf_hi(unsigned int v) { return __uint_as_float(v & 0xffff0000u); }

__device__ __forceinline__ unsigned short f2bf(float x) {
    __hip_bfloat16 b = __float2bfloat16(x);
    return *(unsigned short*)&b;
}

__device__ __forceinline__ unsigned int pack_bf2(float lo, float hi) {
    return ((unsigned int)f2bf(hi) << 16) | (unsigned int)f2bf(lo);
}

// ---------------- fused fp32 -> packed bf16 conversion (node_feats + 4 weights) ---------

__global__ void k_cvt(const f32x4* __restrict__ nf, const float* __restrict__ Wn0,
                      const float* __restrict__ Ws0, const float* __restrict__ Wn1,
                      const float* __restrict__ Ws1, u32x4* __restrict__ nfb,
                      unsigned int* __restrict__ wbf) {
    int i = blockIdx.x * 256 + threadIdx.x;
    const int NNF = N_NODES * D / 8;  // 800000 threads for node feats
    if (i < NNF) {
        f32x4 lo = nf[2 * i];
        f32x4 hi = nf[2 * i + 1];
        u32x4 o;
        o.x = pack_bf2(lo[0], lo[1]);
        o.y = pack_bf2(lo[2], lo[3]);
        o.z = pack_bf2(hi[0], hi[1]);
        o.w = pack_bf2(hi[2], hi[3]);
        nfb[i] = o;
    } else {
        int j = i - NNF;
        if (j < 8192) {  // 4 x 128x128 weights, 8 floats/thread
            int m = j >> 11;
            int t = j & 2047;
            const float* W = (m == 0) ? Wn0 : (m == 1) ? Ws0 : (m == 2) ? Wn1 : Ws1;
            f32x4 lo = ((const f32x4*)W)[2 * t];
            f32x4 hi = ((const f32x4*)W)[2 * t + 1];
            u32x4 o;
            o.x = pack_bf2(lo[0], lo[1]);
            o.y = pack_bf2(lo[2], lo[3]);
            o.z = pack_bf2(hi[0], hi[1]);
            o.w = pack_bf2(hi[2], hi[3]);
            *(u32x4*)(wbf + (size_t)m * 8192 + 4 * t) = o;
        }
    }
}

// ---------------- CSR build ----------------

__global__ void k_count(const int* __restrict__ dst, int* __restrict__ deg) {
    int e = blockIdx.x * 256 + threadIdx.x;
    if (e < N_EDGES) atomicAdd(&deg[dst[e]], 1);
}

// scan1 also emits the iso-node list (deg==0)
__global__ void k_scan1(const int* __restrict__ deg, int* __restrict__ offs,
                        int* __restrict__ part, int* __restrict__ isolist,
                        int* __restrict__ niso) {
    __shared__ int sm[256];
    int t = threadIdx.x;
    int i = blockIdx.x * 256 + t;
    int v = (i < N_NODES) ? deg[i] : 0;
    int orig = v;
    if (i < N_NODES && orig == 0) {
        int p = atomicAdd(niso, 1);
        isolist[p] = i;
    }
    sm[t] = v;
    __syncthreads();
    for (int off = 1; off < 256; off <<= 1) {
        int x = (t >= off) ? sm[t - off] : 0;
        __syncthreads();
        sm[t] += x;
        __syncthreads();
    }
    if (i < N_NODES) offs[i] = sm[t] - orig;  // exclusive within block
    if (t == 255) part[blockIdx.x] = sm[t];   // block total
}

__global__ void k_scan2(int* __restrict__ part, int nb) {
    __shared__ int sm[256];
    int t = threadIdx.x;
    int v = (t < nb) ? part[t] : 0;
    int orig = v;
    sm[t] = v;
    __syncthreads();
    for (int off = 1; off < 256; off <<= 1) {
        int x = (t >= off) ? sm[t - off] : 0;
        __syncthreads();
        sm[t] += x;
        __syncthreads();
    }
    if (t < nb) part[t] = sm[t] - orig;  // exclusive block offsets
}

// scan3 also initializes cur = final offs, so k_fill needs only one atomic
__global__ void k_scan3(int* __restrict__ offs, const int* __restrict__ part,
                        int* __restrict__ cur) {
    int i = blockIdx.x * 256 + threadIdx.x;
    if (i < N_NODES) {
        int v = offs[i] + part[blockIdx.x];
        offs[i] = v;
        cur[i] = v;
    }
}

__global__ void k_fill(const int* __restrict__ src, const int* __restrict__ dst,
                       int* __restrict__ cur, int2* __restrict__ csr) {
    int e = blockIdx.x * 256 + threadIdx.x;
    if (e < N_EDGES) {
        int p = atomicAdd(&cur[dst[e]], 1);
        csr[p] = make_int2(src[e], e);  // (src node, edge id)
    }
}

// ---------------- layer-1 aggregation: 4 edges in flight ----------------
// quarter-wave (16 lanes) per edge; lane covers element group [8g, 8g+8).
// efsum[n] = sum edge_feats (bf16-packed, reused by layer 2)
// pre[n]   = (sum nf_bf16[src] + efsum[n]) / max(deg,1)   (bf16-packed)

__global__ void k_agg_ef(const unsigned int* __restrict__ nfb,  // bf16 [N*64]
                         const f32x4* __restrict__ ef,          // fp32 [E*32]
                         const int2* __restrict__ csr,
                         const int* __restrict__ offs, const int* __restrict__ deg,
                         unsigned int* __restrict__ efsum,
                         unsigned int* __restrict__ pre) {
    int node = blockIdx.x * 4 + (threadIdx.x >> 6);
    if (node >= N_NODES) return;
    int lane = threadIdx.x & 63;
    int q = lane >> 4;  // edge slot within the wave
    int g = lane & 15;  // element group [8g, 8g+8)
    int start = offs[node];
    int cnt = deg[node];
    float ae[8] = {0.f, 0.f, 0.f, 0.f, 0.f, 0.f, 0.f, 0.f};
    float ah[8] = {0.f, 0.f, 0.f, 0.f, 0.f, 0.f, 0.f, 0.f};
#pragma unroll 2
    for (int k = q; k < cnt; k += 4) {
        int2 se = csr[start + k];
        f32x4 e0 = ef[(size_t)se.y * 32 + 2 * g];
        f32x4 e1 = ef[(size_t)se.y * 32 + 2 * g + 1];
        u32x4 hv = *(const u32x4*)(nfb + (size_t)se.x * D2 + 4 * g);
        ae[0] += e0[0];
        ae[1] += e0[1];
        ae[2] += e0[2];
        ae[3] += e0[3];
        ae[4] += e1[0];
        ae[5] += e1[1];
        ae[6] += e1[2];
        ae[7] += e1[3];
        ah[0] += bf_lo(hv.x);
        ah[1] += bf_hi(hv.x);
        ah[2] += bf_lo(hv.y);
        ah[3] += bf_hi(hv.y);
        ah[4] += bf_lo(hv.z);
        ah[5] += bf_hi(hv.z);
        ah[6] += bf_lo(hv.w);
        ah[7] += bf_hi(hv.w);
    }
    // fold the 4 edge slots (lane bits 4,5)
#pragma unroll
    for (int i = 0; i < 8; ++i) {
        ae[i] += __shfl_xor(ae[i], 16);
        ae[i] += __shfl_xor(ae[i], 32);
        ah[i] += __shfl_xor(ah[i], 16);
        ah[i] += __shfl_xor(ah[i], 32);
    }
    float inv = 1.0f / fmaxf((float)cnt, 1.0f);
    if (q == 0) {
        u32x4 eo;
        eo.x = pack_bf2(ae[0], ae[1]);
        eo.y = pack_bf2(ae[2], ae[3]);
        eo.z = pack_bf2(ae[4], ae[5]);
        eo.w = pack_bf2(ae[6], ae[7]);
        *(u32x4*)(efsum + (size_t)node * D2 + 4 * g) = eo;
    } else if (q == 1) {
        u32x4 po;
        po.x = pack_bf2((ah[0] + ae[0]) * inv, (ah[1] + ae[1]) * inv);
        po.y = pack_bf2((ah[2] + ae[2]) * inv, (ah[3] + ae[3]) * inv);
        po.z = pack_bf2((ah[4] + ae[4]) * inv, (ah[5] + ae[5]) * inv);
        po.w = pack_bf2((ah[6] + ae[6]) * inv, (ah[7] + ae[7]) * inv);
        *(u32x4*)(pre + (size_t)node * D2 + 4 * g) = po;
    }
}

// ---------------- layer-2 aggregation: 8 edges in flight ----------------
// eighth-wave (8 lanes) per edge; lane covers element group [16g, 16g+16).

__global__ void k_agg2(const unsigned int* __restrict__ h,  // h1 bf16 [N*64]
                       const int2* __restrict__ csr,
                       const int* __restrict__ offs, const int* __restrict__ deg,
                       const unsigned int* __restrict__ efsum,
                       unsigned int* __restrict__ pre) {
    int node = blockIdx.x * 4 + (threadIdx.x >> 6);
    if (node >= N_NODES) return;
    int lane = threadIdx.x & 63;
    int e = lane >> 3;  // edge slot
    int g = lane & 7;   // element group [16g, 16g+16)
    int start = offs[node];
    int cnt = deg[node];
    float a[16];
#pragma unroll
    for (int i = 0; i < 16; ++i) a[i] = 0.f;
#pragma unroll 2
    for (int k = e; k < cnt; k += 8) {
        int2 se = csr[start + k];
        u32x4 h0 = *(const u32x4*)(h + (size_t)se.x * D2 + 8 * g);
        u32x4 h1v = *(const u32x4*)(h + (size_t)se.x * D2 + 8 * g + 4);
        a[0] += bf_lo(h0.x);
        a[1] += bf_hi(h0.x);
        a[2] += bf_lo(h0.y);
        a[3] += bf_hi(h0.y);
        a[4] += bf_lo(h0.z);
        a[5] += bf_hi(h0.z);
        a[6] += bf_lo(h0.w);
        a[7] += bf_hi(h0.w);
        a[8] += bf_lo(h1v.x);
        a[9] += bf_hi(h1v.x);
        a[10] += bf_lo(h1v.y);
        a[11] += bf_hi(h1v.y);
        a[12] += bf_lo(h1v.z);
        a[13] += bf_hi(h1v.z);
        a[14] += bf_lo(h1v.w);
        a[15] += bf_hi(h1v.w);
    }
    // fold the 8 edge slots (lane bits 3,4,5)
#pragma unroll
    for (int i = 0; i < 16; ++i) {
        a[i] += __shfl_xor(a[i], 8);
        a[i] += __shfl_xor(a[i], 16);
        a[i] += __shfl_xor(a[i], 32);
    }
    if (e == 0) {
        u32x4 e0 = *(const u32x4*)(efsum + (size_t)node * D2 + 8 * g);
        u32x4 e1 = *(const u32x4*)(efsum + (size_t)node * D2 + 8 * g + 4);
        float inv = 1.0f / fmaxf((float)cnt, 1.0f);
        u32x4 o0, o1;
        o0.x = pack_bf2((a[0] + bf_lo(e0.x)) * inv, (a[1] + bf_hi(e0.x)) * inv);
        o0.y = pack_bf2((a[2] + bf_lo(e0.y)) * inv, (a[3] + bf_hi(e0.y)) * inv);
        o0.z = pack_bf2((a[4] + bf_lo(e0.z)) * inv, (a[5] + bf_hi(e0.z)) * inv);
        o0.w = pack_bf2((a[6] + bf_lo(e0.w)) * inv, (a[7] + bf_hi(e0.w)) * inv);
        o1.x = pack_bf2((a[8] + bf_lo(e1.x)) * inv, (a[9] + bf_hi(e1.x)) * inv);
        o1.y = pack_bf2((a[10] + bf_lo(e1.y)) * inv, (a[11] + bf_hi(e1.y)) * inv);
        o1.z = pack_bf2((a[12] + bf_lo(e1.z)) * inv, (a[13] + bf_hi(e1.z)) * inv);
        o1.w = pack_bf2((a[14] + bf_lo(e1.w)) * inv, (a[15] + bf_hi(e1.w)) * inv);
        *(u32x4*)(pre + (size_t)node * D2 + 8 * g) = o0;
        *(u32x4*)(pre + (size_t)node * D2 + 8 * g + 4) = o1;
    }
}

// ---------------- fused GEMM: out = leaky(pre@Wn^T + h@Ws^T) ----------------
// NT GEMM, M=50000, N=128, K=256 ([pre|h] @ [Wn|Ws]^T). All operands bf16.
// 16 rows per wave -> 3126 waves for TLP.

template <int OUT_F32>
__global__ void k_gemm(const unsigned short* __restrict__ A1,  // pre [M,128] bf16
                       const unsigned short* __restrict__ A2,  // h   [M,128] bf16
                       const unsigned short* __restrict__ W1,  // Wn bf16
                       const unsigned short* __restrict__ W2,  // Ws bf16
                       void* __restrict__ outv) {
    int wave = threadIdx.x >> 6;
    int lane = threadIdx.x & 63;
    int quad = lane >> 4;
    int r16 = lane & 15;
    int m0 = (blockIdx.x * 4 + wave) * 16;  // 16 rows per wave

    f32x4 acc[8];
#pragma unroll
    for (int nt = 0; nt < 8; ++nt) acc[nt] = (f32x4){0.f, 0.f, 0.f, 0.f};

    int rowA = min(m0 + r16, N_NODES - 1);

#pragma unroll
    for (int ks = 0; ks < 8; ++ks) {
        int koff = (ks & 3) * 32 + quad * 8;  // lane's 8 contiguous k
        const unsigned short* Asrc = (ks < 4) ? A1 : A2;
        bf16x8 a = *(const bf16x8*)(Asrc + (size_t)rowA * D + koff);
        const unsigned short* Wsrc = (ks < 4) ? W1 : W2;
#pragma unroll
        for (int nt = 0; nt < 8; ++nt) {
            bf16x8 b = *(const bf16x8*)(Wsrc + (size_t)(nt * 16 + r16) * D + koff);
            acc[nt] = __builtin_amdgcn_mfma_f32_16x16x32_bf16(a, b, acc[nt], 0, 0, 0);
        }
    }

    // C/D layout: col = lane&15, row = quad*4 + reg (m89/m91-verified)
#pragma unroll
    for (int r = 0; r < 4; ++r) {
        int row = m0 + quad * 4 + r;
        if (row < N_NODES) {
#pragma unroll
            for (int nt = 0; nt < 8; ++nt) {
                float x = acc[nt][r];
                x = (x >= 0.f) ? x : x * SLOPE;
                if (OUT_F32)
                    ((float*)outv)[(size_t)row * D + nt * 16 + r16] = x;
                else
                    ((unsigned short*)outv)[(size_t)row * D + nt * 16 + r16] = f2bf(x);
            }
        }
    }
}

// iso nodes (deg==0): out[n] = leaky(h[n] @ Wi^T), overwriting the GEMM value.
// Driven by the iso list; expected empty, so these are ~free.

__global__ void k_fixup1(const unsigned int* __restrict__ nfb,  // node_feats bf16
                         const float* __restrict__ Wi,          // fp32
                         const int* __restrict__ isolist, const int* __restrict__ niso,
                         unsigned short* __restrict__ out) {  // h1 bf16
    int w = blockIdx.x * 4 + (threadIdx.x >> 6);
    int lane = threadIdx.x & 63;
    int n = *niso;
    for (int t = w; t < n; t += gridDim.x * 4) {
        int node = isolist[t];
        const unsigned int* hrow = nfb + (size_t)node * D2;
        float a0 = 0.f, a1 = 0.f;
        for (int ku = 0; ku < D2; ++ku) {
            unsigned int v = hrow[ku];
            float h0 = bf_lo(v), h1 = bf_hi(v);
            a0 += h0 * Wi[(size_t)lane * D + 2 * ku] + h1 * Wi[(size_t)lane * D + 2 * ku + 1];
            a1 += h0 * Wi[(size_t)(lane + 64) * D + 2 * ku] +
                  h1 * Wi[(size_t)(lane + 64) * D + 2 * ku + 1];
        }
        a0 = (a0 >= 0.f) ? a0 : a0 * SLOPE;
        a1 = (a1 >= 0.f) ? a1 : a1 * SLOPE;
        out[(size_t)node * D + lane] = f2bf(a0);
        out[(size_t)node * D + lane + 64] = f2bf(a1);
    }
}

__global__ void k_fixup2(const unsigned short* __restrict__ h,  // h1 bf16
                         const float* __restrict__ Wi,          // fp32
                         const int* __restrict__ isolist, const int* __restrict__ niso,
                         float* __restrict__ out) {  // d_out fp32
    int w = blockIdx.x * 4 + (threadIdx.x >> 6);
    int lane = threadIdx.x & 63;
    int n = *niso;
    for (int t = w; t < n; t += gridDim.x * 4) {
        int node = isolist[t];
        const unsigned short* hrow = h + (size_t)node * D;
        float a0 = 0.f, a1 = 0.f;
        for (int k = 0; k < D; ++k) {
            float hk = __uint_as_float(((unsigned int)hrow[k]) << 16);
            a0 += hk * Wi[(size_t)lane * D + k];
            a1 += hk * Wi[(size_t)(lane + 64) * D + k];
        }
        a0 = (a0 >= 0.f) ? a0 : a0 * SLOPE;
        a1 = (a1 >= 0.f) ? a1 : a1 * SLOPE;
        out[(size_t)node * D + lane] = a0;
        out[(size_t)node * D + lane + 64] = a1;
    }
}

// ---------------- launch ----------------

extern "C" void kernel_launch(void* const* d_in, const int* in_sizes, int n_in,
                              void* d_out, int out_size, void* d_ws, size_t ws_size,
                              hipStream_t stream) {
    const float* node_feats = (const float*)d_in[0];
    const float* edge_feats = (const float*)d_in[1];
    const int* src = (const int*)d_in[2];
    const int* dst = (const int*)d_in[3];
    const float* Wn0 = (const float*)d_in[4];
    const float* Ws0 = (const float*)d_in[5];
    const float* Wi0 = (const float*)d_in[6];
    const float* Wn1 = (const float*)d_in[7];
    const float* Ws1 = (const float*)d_in[8];
    const float* Wi1 = (const float*)d_in[9];

    char* ws = (char*)d_ws;
    size_t o = 0;
    auto alloc = [&](size_t bytes) -> char* {
        char* p = ws + o;
        o += (bytes + 255) & ~size_t(255);
        return p;
    };
    int* deg = (int*)alloc((size_t)N_NODES * 4);  // zeroed
    int* niso = (int*)alloc(256);                 // zeroed (contiguous with deg)
    int* cur = (int*)alloc((size_t)N_NODES * 4);  // init by k_scan3
    int* offs = (int*)alloc((size_t)N_NODES * 4);
    int* part = (int*)alloc(1024);
    int* isolist = (int*)alloc((size_t)N_NODES * 4);
    int2* csr = (int2*)alloc((size_t)N_EDGES * 8);                        //  6.4 MB
    unsigned int* efsum = (unsigned int*)alloc((size_t)N_NODES * D * 2);  // 12.8 MB
    unsigned int* pre = (unsigned int*)alloc((size_t)N_NODES * D * 2);    // 12.8 MB
    unsigned int* h1 = (unsigned int*)alloc((size_t)N_NODES * D * 2);     // 12.8 MB
    unsigned int* nfb = (unsigned int*)alloc((size_t)N_NODES * D * 2);    // 12.8 MB
    unsigned int* wbf = (unsigned int*)alloc(4 * 8192 * 4);               // 128 KB

    // zero deg + niso (contiguous allocations)
    hipMemsetAsync(deg, 0, (((size_t)N_NODES * 4 + 255) & ~size_t(255)) + 256, stream);

    int ebl = (N_EDGES + 255) / 256;  // 3125
    int nbl = (N_NODES + 255) / 256;  // 196
    int nwb = (N_NODES + 3) / 4;      // 12500 (4 waves/block, wave-per-node)
    int gbl = (N_NODES + 63) / 64;    // 782 (64 rows/block, 16/wave)
    int cbl = (N_NODES * D / 8 + 8192 + 255) / 256;

    k_cvt<<<cbl, 256, 0, stream>>>((const f32x4*)node_feats, Wn0, Ws0, Wn1, Ws1,
                                   (u32x4*)nfb, wbf);
    k_count<<<ebl, 256, 0, stream>>>(dst, deg);
    k_scan1<<<nbl, 256, 0, stream>>>(deg, offs, part, isolist, niso);
    k_scan2<<<1, 256, 0, stream>>>(part, nbl);
    k_scan3<<<nbl, 256, 0, stream>>>(offs, part, cur);
    k_fill<<<ebl, 256, 0, stream>>>(src, dst, cur, csr);

    const unsigned short* Wn0b = (const unsigned short*)(wbf + 0 * 8192);
    const unsigned short* Ws0b = (const unsigned short*)(wbf + 1 * 8192);
    const unsigned short* Wn1b = (const unsigned short*)(wbf + 2 * 8192);
    const unsigned short* Ws1b = (const unsigned short*)(wbf + 3 * 8192);

    // layer 1: nfb (bf16) -> h1 (bf16); also builds efsum (bf16)
    k_agg_ef<<<nwb, 256, 0, stream>>>(nfb, (const f32x4*)edge_feats, csr, offs, deg, efsum, pre);
    k_gemm<0><<<gbl, 256, 0, stream>>>((const unsigned short*)pre, (const unsigned short*)nfb,
                                       Wn0b, Ws0b, (void*)h1);
    k_fixup1<<<32, 256, 0, stream>>>(nfb, Wi0, isolist, niso, (unsigned short*)h1);

    // layer 2: h1 (bf16) -> d_out (fp32)
    k_agg2<<<nwb, 256, 0, stream>>>(h1, csr, offs, deg, efsum, pre);
    k_gemm<1><<<gbl, 256, 0, stream>>>((const unsigned short*)pre, (const unsigned short*)h1,
                                       Wn1b, Ws1b, d_out);
    k_fixup2<<<32, 256, 0, stream>>>((const unsigned short*)h1, Wi1, isolist, niso, (float*)d_out);
}

// Round 3
// 748.954 us; speedup vs baseline: 1.0450x; 1.0450x over previous
//
#include <hip/hip_runtime.h>
#include <hip/hip_bf16.h>

#define N_NODES 50000
#define N_EDGES 800000
#define D 128
#define D2 64  // packed-uint (2×bf16) per row

static constexpr float SLOPE = 11.0f / 48.0f;  // eval-mode RReLU mean slope

typedef __attribute__((ext_vector_type(8))) short bf16x8;
typedef __attribute__((ext_vector_type(4))) float f32x4;
typedef __attribute__((ext_vector_type(2))) unsigned int u32x2;
typedef __attribute__((ext_vector_type(4))) unsigned int u32x4;

__device__ __forceinline__ float bf_lo(unsigned int v) { return __uint_as_float(v << 16); }
__device__ __forceinline__ float bf_hi(unsigned int v) { return __uint_as_float(v & 0xffff0000u); }

__device__ __forceinline__ unsigned short f2bf(float x) {
    __hip_bfloat16 b = __float2bfloat16(x);
    return *(unsigned short*)&b;
}

__device__ __forceinline__ unsigned int pack_bf2(float lo, float hi) {
    return ((unsigned int)f2bf(hi) << 16) | (unsigned int)f2bf(lo);
}

// ------- fused: fp32->bf16 conversion (node_feats + 4 weights) AND degree count -------
// thread ranges: [0, 800000) nf cvt (8 floats each), [800000, 808192) weights,
// [808192, 1608192) edge degree count. All independent.

__global__ void k_cvt_count(const f32x4* __restrict__ nf, const float* __restrict__ Wn0,
                            const float* __restrict__ Ws0, const float* __restrict__ Wn1,
                            const float* __restrict__ Ws1, const int* __restrict__ dst,
                            u32x4* __restrict__ nfb, unsigned int* __restrict__ wbf,
                            int* __restrict__ deg) {
    int i = blockIdx.x * 256 + threadIdx.x;
    const int NNF = N_NODES * D / 8;  // 800000
    if (i < NNF) {
        f32x4 lo = nf[2 * i];
        f32x4 hi = nf[2 * i + 1];
        u32x4 o;
        o.x = pack_bf2(lo[0], lo[1]);
        o.y = pack_bf2(lo[2], lo[3]);
        o.z = pack_bf2(hi[0], hi[1]);
        o.w = pack_bf2(hi[2], hi[3]);
        nfb[i] = o;
    } else if (i < NNF + 8192) {
        int j = i - NNF;
        int m = j >> 11;
        int t = j & 2047;
        const float* W = (m == 0) ? Wn0 : (m == 1) ? Ws0 : (m == 2) ? Wn1 : Ws1;
        f32x4 lo = ((const f32x4*)W)[2 * t];
        f32x4 hi = ((const f32x4*)W)[2 * t + 1];
        u32x4 o;
        o.x = pack_bf2(lo[0], lo[1]);
        o.y = pack_bf2(lo[2], lo[3]);
        o.z = pack_bf2(hi[0], hi[1]);
        o.w = pack_bf2(hi[2], hi[3]);
        *(u32x4*)(wbf + (size_t)m * 8192 + 4 * t) = o;
    } else {
        int e = i - NNF - 8192;
        if (e < N_EDGES) atomicAdd(&deg[dst[e]], 1);
    }
}

// ---------------- CSR build ----------------

// scan1 also emits the iso-node list (deg==0)
__global__ void k_scan1(const int* __restrict__ deg, int* __restrict__ offs,
                        int* __restrict__ part, int* __restrict__ isolist,
                        int* __restrict__ niso) {
    __shared__ int sm[256];
    int t = threadIdx.x;
    int i = blockIdx.x * 256 + t;
    int v = (i < N_NODES) ? deg[i] : 0;
    int orig = v;
    if (i < N_NODES && orig == 0) {
        int p = atomicAdd(niso, 1);
        isolist[p] = i;
    }
    sm[t] = v;
    __syncthreads();
    for (int off = 1; off < 256; off <<= 1) {
        int x = (t >= off) ? sm[t - off] : 0;
        __syncthreads();
        sm[t] += x;
        __syncthreads();
    }
    if (i < N_NODES) offs[i] = sm[t] - orig;  // exclusive within block
    if (t == 255) part[blockIdx.x] = sm[t];   // block total
}

__global__ void k_scan2(int* __restrict__ part, int nb) {
    __shared__ int sm[256];
    int t = threadIdx.x;
    int v = (t < nb) ? part[t] : 0;
    int orig = v;
    sm[t] = v;
    __syncthreads();
    for (int off = 1; off < 256; off <<= 1) {
        int x = (t >= off) ? sm[t - off] : 0;
        __syncthreads();
        sm[t] += x;
        __syncthreads();
    }
    if (t < nb) part[t] = sm[t] - orig;  // exclusive block offsets
}

// scan3 also initializes cur = final offs, so k_fill needs only one atomic
__global__ void k_scan3(int* __restrict__ offs, const int* __restrict__ part,
                        int* __restrict__ cur) {
    int i = blockIdx.x * 256 + threadIdx.x;
    if (i < N_NODES) {
        int v = offs[i] + part[blockIdx.x];
        offs[i] = v;
        cur[i] = v;
    }
}

__global__ void k_fill(const int* __restrict__ src, const int* __restrict__ dst,
                       int* __restrict__ cur, int2* __restrict__ csr) {
    int e = blockIdx.x * 256 + threadIdx.x;
    if (e < N_EDGES) {
        int p = atomicAdd(&cur[dst[e]], 1);
        csr[p] = make_int2(src[e], e);  // (src node, edge id)
    }
}

// ---------------- layer-1 aggregation: 2 edge slots, unroll 4 ----------------
// half-wave (32 lanes) per edge; lane covers element group [4c, 4c+4).
// efsum[n] = sum edge_feats (bf16-packed, reused by layer 2)
// pre[n]   = (sum nf_bf16[src] + efsum[n]) / max(deg,1)   (bf16-packed)

__global__ void k_agg_ef(const unsigned int* __restrict__ nfb,  // bf16 [N*64]
                         const f32x4* __restrict__ ef,          // fp32 [E*32]
                         const int2* __restrict__ csr,
                         const int* __restrict__ offs, const int* __restrict__ deg,
                         unsigned int* __restrict__ efsum,
                         unsigned int* __restrict__ pre) {
    int node = blockIdx.x * 4 + (threadIdx.x >> 6);
    if (node >= N_NODES) return;
    int lane = threadIdx.x & 63;
    int half = lane >> 5;  // which edge of the pair this lane handles
    int c = lane & 31;     // element group [4c, 4c+4)
    int start = offs[node];
    int cnt = deg[node];
    f32x4 ae = {0.f, 0.f, 0.f, 0.f};
    f32x4 ah = {0.f, 0.f, 0.f, 0.f};
#pragma unroll 4
    for (int k = half; k < cnt; k += 2) {
        int2 se = csr[start + k];
        f32x4 ev = ef[(size_t)se.y * 32 + c];
        u32x2 hv = *(const u32x2*)(nfb + (size_t)se.x * D2 + 2 * c);
        ae[0] += ev[0];
        ae[1] += ev[1];
        ae[2] += ev[2];
        ae[3] += ev[3];
        ah[0] += bf_lo(hv.x);
        ah[1] += bf_hi(hv.x);
        ah[2] += bf_lo(hv.y);
        ah[3] += bf_hi(hv.y);
    }
    // combine the two halves
#pragma unroll
    for (int i = 0; i < 4; ++i) {
        ae[i] += __shfl_xor(ae[i], 32);
        ah[i] += __shfl_xor(ah[i], 32);
    }
    float inv = 1.0f / fmaxf((float)cnt, 1.0f);
    if (half == 0) {
        u32x2 eo;
        eo.x = pack_bf2(ae[0], ae[1]);
        eo.y = pack_bf2(ae[2], ae[3]);
        *(u32x2*)(efsum + (size_t)node * D2 + 2 * c) = eo;
    } else {
        u32x2 po;
        po.x = pack_bf2((ah[0] + ae[0]) * inv, (ah[1] + ae[1]) * inv);
        po.y = pack_bf2((ah[2] + ae[2]) * inv, (ah[3] + ae[3]) * inv);
        *(u32x2*)(pre + (size_t)node * D2 + 2 * c) = po;
    }
}

// ---------------- layer-2 aggregation: 4 edge slots ----------------
// quarter-wave (16 lanes) per edge; lane covers element group [8g, 8g+8).

__global__ void k_agg2(const unsigned int* __restrict__ h,  // h1 bf16 [N*64]
                       const int2* __restrict__ csr,
                       const int* __restrict__ offs, const int* __restrict__ deg,
                       const unsigned int* __restrict__ efsum,
                       unsigned int* __restrict__ pre) {
    int node = blockIdx.x * 4 + (threadIdx.x >> 6);
    if (node >= N_NODES) return;
    int lane = threadIdx.x & 63;
    int q = lane >> 4;  // which edge of the quad
    int g = lane & 15;  // element group [8g, 8g+8)
    int start = offs[node];
    int cnt = deg[node];
    float a[8] = {0.f, 0.f, 0.f, 0.f, 0.f, 0.f, 0.f, 0.f};
#pragma unroll 2
    for (int k = q; k < cnt; k += 4) {
        int2 se = csr[start + k];
        u32x4 hv = *(const u32x4*)(h + (size_t)se.x * D2 + 4 * g);
        a[0] += bf_lo(hv.x);
        a[1] += bf_hi(hv.x);
        a[2] += bf_lo(hv.y);
        a[3] += bf_hi(hv.y);
        a[4] += bf_lo(hv.z);
        a[5] += bf_hi(hv.z);
        a[6] += bf_lo(hv.w);
        a[7] += bf_hi(hv.w);
    }
    // combine the four quarters
#pragma unroll
    for (int i = 0; i < 8; ++i) {
        a[i] += __shfl_xor(a[i], 16);
        a[i] += __shfl_xor(a[i], 32);
    }
    if (q == 0) {
        u32x4 es = *(const u32x4*)(efsum + (size_t)node * D2 + 4 * g);
        float inv = 1.0f / fmaxf((float)cnt, 1.0f);
        float r0 = (a[0] + bf_lo(es.x)) * inv;
        float r1 = (a[1] + bf_hi(es.x)) * inv;
        float r2 = (a[2] + bf_lo(es.y)) * inv;
        float r3 = (a[3] + bf_hi(es.y)) * inv;
        float r4 = (a[4] + bf_lo(es.z)) * inv;
        float r5 = (a[5] + bf_hi(es.z)) * inv;
        float r6 = (a[6] + bf_lo(es.w)) * inv;
        float r7 = (a[7] + bf_hi(es.w)) * inv;
        u32x4 o;
        o.x = pack_bf2(r0, r1);
        o.y = pack_bf2(r2, r3);
        o.z = pack_bf2(r4, r5);
        o.w = pack_bf2(r6, r7);
        *(u32x4*)(pre + (size_t)node * D2 + 4 * g) = o;
    }
}

// ---------------- fused GEMM: out = leaky(pre@Wn^T + h@Ws^T) ----------------
// NT GEMM, M=50000, N=128, K=256 ([pre|h] @ [Wn|Ws]^T). All operands bf16.
// 32 rows per wave (2 m-tiles) — measured-best config.

template <int OUT_F32>
__global__ void k_gemm(const unsigned short* __restrict__ A1,  // pre [M,128] bf16
                       const unsigned short* __restrict__ A2,  // h   [M,128] bf16
                       const unsigned short* __restrict__ W1,  // Wn bf16
                       const unsigned short* __restrict__ W2,  // Ws bf16
                       void* __restrict__ outv) {
    int wave = threadIdx.x >> 6;
    int lane = threadIdx.x & 63;
    int quad = lane >> 4;
    int r16 = lane & 15;
    int m0 = (blockIdx.x * 4 + wave) * 32;  // 32 rows per wave (2 m-tiles)

    f32x4 acc[2][8];
#pragma unroll
    for (int mt = 0; mt < 2; ++mt)
#pragma unroll
        for (int nt = 0; nt < 8; ++nt) acc[mt][nt] = (f32x4){0.f, 0.f, 0.f, 0.f};

    int rowA0 = min(m0 + r16, N_NODES - 1);
    int rowA1 = min(m0 + 16 + r16, N_NODES - 1);

#pragma unroll
    for (int ks = 0; ks < 8; ++ks) {
        int koff = (ks & 3) * 32 + quad * 8;  // lane's 8 contiguous k
        const unsigned short* Asrc = (ks < 4) ? A1 : A2;
        bf16x8 a0 = *(const bf16x8*)(Asrc + (size_t)rowA0 * D + koff);
        bf16x8 a1 = *(const bf16x8*)(Asrc + (size_t)rowA1 * D + koff);
        const unsigned short* Wsrc = (ks < 4) ? W1 : W2;
#pragma unroll
        for (int nt = 0; nt < 8; ++nt) {
            bf16x8 b = *(const bf16x8*)(Wsrc + (size_t)(nt * 16 + r16) * D + koff);
            acc[0][nt] = __builtin_amdgcn_mfma_f32_16x16x32_bf16(a0, b, acc[0][nt], 0, 0, 0);
            acc[1][nt] = __builtin_amdgcn_mfma_f32_16x16x32_bf16(a1, b, acc[1][nt], 0, 0, 0);
        }
    }

    // C/D layout: col = lane&15, row = quad*4 + reg (m89/m91-verified)
#pragma unroll
    for (int mt = 0; mt < 2; ++mt) {
#pragma unroll
        for (int r = 0; r < 4; ++r) {
            int row = m0 + mt * 16 + quad * 4 + r;
            if (row < N_NODES) {
#pragma unroll
                for (int nt = 0; nt < 8; ++nt) {
                    float x = acc[mt][nt][r];
                    x = (x >= 0.f) ? x : x * SLOPE;
                    if (OUT_F32)
                        ((float*)outv)[(size_t)row * D + nt * 16 + r16] = x;
                    else
                        ((unsigned short*)outv)[(size_t)row * D + nt * 16 + r16] = f2bf(x);
                }
            }
        }
    }
}

// iso nodes (deg==0): out[n] = leaky(h[n] @ Wi^T), overwriting the GEMM value.
// Driven by the iso list; expected empty, so these are ~free.

__global__ void k_fixup1(const unsigned int* __restrict__ nfb,  // node_feats bf16
                         const float* __restrict__ Wi,          // fp32
                         const int* __restrict__ isolist, const int* __restrict__ niso,
                         unsigned short* __restrict__ out) {  // h1 bf16
    int w = blockIdx.x * 4 + (threadIdx.x >> 6);
    int lane = threadIdx.x & 63;
    int n = *niso;
    for (int t = w; t < n; t += gridDim.x * 4) {
        int node = isolist[t];
        const unsigned int* hrow = nfb + (size_t)node * D2;
        float a0 = 0.f, a1 = 0.f;
        for (int ku = 0; ku < D2; ++ku) {
            unsigned int v = hrow[ku];
            float h0 = bf_lo(v), h1 = bf_hi(v);
            a0 += h0 * Wi[(size_t)lane * D + 2 * ku] + h1 * Wi[(size_t)lane * D + 2 * ku + 1];
            a1 += h0 * Wi[(size_t)(lane + 64) * D + 2 * ku] +
                  h1 * Wi[(size_t)(lane + 64) * D + 2 * ku + 1];
        }
        a0 = (a0 >= 0.f) ? a0 : a0 * SLOPE;
        a1 = (a1 >= 0.f) ? a1 : a1 * SLOPE;
        out[(size_t)node * D + lane] = f2bf(a0);
        out[(size_t)node * D + lane + 64] = f2bf(a1);
    }
}

__global__ void k_fixup2(const unsigned short* __restrict__ h,  // h1 bf16
                         const float* __restrict__ Wi,          // fp32
                         const int* __restrict__ isolist, const int* __restrict__ niso,
                         float* __restrict__ out) {  // d_out fp32
    int w = blockIdx.x * 4 + (threadIdx.x >> 6);
    int lane = threadIdx.x & 63;
    int n = *niso;
    for (int t = w; t < n; t += gridDim.x * 4) {
        int node = isolist[t];
        const unsigned short* hrow = h + (size_t)node * D;
        float a0 = 0.f, a1 = 0.f;
        for (int k = 0; k < D; ++k) {
            float hk = __uint_as_float(((unsigned int)hrow[k]) << 16);
            a0 += hk * Wi[(size_t)lane * D + k];
            a1 += hk * Wi[(size_t)(lane + 64) * D + k];
        }
        a0 = (a0 >= 0.f) ? a0 : a0 * SLOPE;
        a1 = (a1 >= 0.f) ? a1 : a1 * SLOPE;
        out[(size_t)node * D + lane] = a0;
        out[(size_t)node * D + lane + 64] = a1;
    }
}

// ---------------- launch ----------------

extern "C" void kernel_launch(void* const* d_in, const int* in_sizes, int n_in,
                              void* d_out, int out_size, void* d_ws, size_t ws_size,
                              hipStream_t stream) {
    const float* node_feats = (const float*)d_in[0];
    const float* edge_feats = (const float*)d_in[1];
    const int* src = (const int*)d_in[2];
    const int* dst = (const int*)d_in[3];
    const float* Wn0 = (const float*)d_in[4];
    const float* Ws0 = (const float*)d_in[5];
    const float* Wi0 = (const float*)d_in[6];
    const float* Wn1 = (const float*)d_in[7];
    const float* Ws1 = (const float*)d_in[8];
    const float* Wi1 = (const float*)d_in[9];

    char* ws = (char*)d_ws;
    size_t o = 0;
    auto alloc = [&](size_t bytes) -> char* {
        char* p = ws + o;
        o += (bytes + 255) & ~size_t(255);
        return p;
    };
    int* deg = (int*)alloc((size_t)N_NODES * 4);  // zeroed
    int* niso = (int*)alloc(256);                 // zeroed (contiguous with deg)
    int* cur = (int*)alloc((size_t)N_NODES * 4);  // init by k_scan3
    int* offs = (int*)alloc((size_t)N_NODES * 4);
    int* part = (int*)alloc(1024);
    int* isolist = (int*)alloc((size_t)N_NODES * 4);
    int2* csr = (int2*)alloc((size_t)N_EDGES * 8);                        //  6.4 MB
    unsigned int* efsum = (unsigned int*)alloc((size_t)N_NODES * D * 2);  // 12.8 MB
    unsigned int* pre = (unsigned int*)alloc((size_t)N_NODES * D * 2);    // 12.8 MB
    unsigned int* h1 = (unsigned int*)alloc((size_t)N_NODES * D * 2);     // 12.8 MB
    unsigned int* nfb = (unsigned int*)alloc((size_t)N_NODES * D * 2);    // 12.8 MB
    unsigned int* wbf = (unsigned int*)alloc(4 * 8192 * 4);               // 128 KB

    // zero deg + niso (contiguous allocations)
    hipMemsetAsync(deg, 0, (((size_t)N_NODES * 4 + 255) & ~size_t(255)) + 256, stream);

    int nbl = (N_NODES + 255) / 256;  // 196
    int nwb = (N_NODES + 3) / 4;      // 12500 (4 waves/block, wave-per-node)
    int gbl = (N_NODES + 127) / 128;  // 391 (128 rows/block, 32/wave)
    int ccbl = (N_NODES * D / 8 + 8192 + N_EDGES + 255) / 256;  // 6282
    int ebl = (N_EDGES + 255) / 256;  // 3125

    k_cvt_count<<<ccbl, 256, 0, stream>>>((const f32x4*)node_feats, Wn0, Ws0, Wn1, Ws1, dst,
                                          (u32x4*)nfb, wbf, deg);
    k_scan1<<<nbl, 256, 0, stream>>>(deg, offs, part, isolist, niso);
    k_scan2<<<1, 256, 0, stream>>>(part, nbl);
    k_scan3<<<nbl, 256, 0, stream>>>(offs, part, cur);
    k_fill<<<ebl, 256, 0, stream>>>(src, dst, cur, csr);

    const unsigned short* Wn0b = (const unsigned short*)(wbf + 0 * 8192);
    const unsigned short* Ws0b = (const unsigned short*)(wbf + 1 * 8192);
    const unsigned short* Wn1b = (const unsigned short*)(wbf + 2 * 8192);
    const unsigned short* Ws1b = (const unsigned short*)(wbf + 3 * 8192);

    // layer 1: nfb (bf16) -> h1 (bf16); also builds efsum (bf16)
    k_agg_ef<<<nwb, 256, 0, stream>>>(nfb, (const f32x4*)edge_feats, csr, offs, deg, efsum, pre);
    k_gemm<0><<<gbl, 256, 0, stream>>>((const unsigned short*)pre, (const unsigned short*)nfb,
                                       Wn0b, Ws0b, (void*)h1);
    k_fixup1<<<32, 256, 0, stream>>>(nfb, Wi0, isolist, niso, (unsigned short*)h1);

    // layer 2: h1 (bf16) -> d_out (fp32)
    k_agg2<<<nwb, 256, 0, stream>>>(h1, csr, offs, deg, efsum, pre);
    k_gemm<1><<<gbl, 256, 0, stream>>>((const unsigned short*)pre, (const unsigned short*)h1,
                                       Wn1b, Ws1b, d_out);
    k_fixup2<<<32, 256, 0, stream>>>((const unsigned short*)h1, Wi1, isolist, niso, (float*)d_out);
}

// Round 4
// 730.109 us; speedup vs baseline: 1.0720x; 1.0258x over previous
//
#include <hip/hip_runtime.h>
#include <hip/hip_bf16.h>

#define N_NODES 50000
#define N_EDGES 800000
#define D 128
#define D2 64  // packed-uint (2×bf16) per row

static constexpr float SLOPE = 11.0f / 48.0f;  // eval-mode RReLU mean slope

typedef __attribute__((ext_vector_type(8))) short bf16x8;
typedef __attribute__((ext_vector_type(4))) float f32x4;
typedef __attribute__((ext_vector_type(2))) unsigned int u32x2;
typedef __attribute__((ext_vector_type(4))) unsigned int u32x4;

__device__ __forceinline__ float bf_lo(unsigned int v) { return __uint_as_float(v << 16); }
__device__ __forceinline__ float bf_hi(unsigned int v) { return __uint_as_float(v & 0xffff0000u); }

__device__ __forceinline__ unsigned short f2bf(float x) {
    __hip_bfloat16 b = __float2bfloat16(x);
    return *(unsigned short*)&b;
}

__device__ __forceinline__ unsigned int pack_bf2(float lo, float hi) {
    return ((unsigned int)f2bf(hi) << 16) | (unsigned int)f2bf(lo);
}

// ------- fused: fp32->bf16 conversion (node_feats + 4 weights) AND degree count -------
// thread ranges: [0, 800000) nf cvt (8 floats each), [800000, 808192) weights,
// [808192, 1608192) edge degree count. All independent.

__global__ void k_cvt_count(const f32x4* __restrict__ nf, const float* __restrict__ Wn0,
                            const float* __restrict__ Ws0, const float* __restrict__ Wn1,
                            const float* __restrict__ Ws1, const int* __restrict__ dst,
                            u32x4* __restrict__ nfb, unsigned int* __restrict__ wbf,
                            int* __restrict__ deg) {
    int i = blockIdx.x * 256 + threadIdx.x;
    const int NNF = N_NODES * D / 8;  // 800000
    if (i < NNF) {
        f32x4 lo = nf[2 * i];
        f32x4 hi = nf[2 * i + 1];
        u32x4 o;
        o.x = pack_bf2(lo[0], lo[1]);
        o.y = pack_bf2(lo[2], lo[3]);
        o.z = pack_bf2(hi[0], hi[1]);
        o.w = pack_bf2(hi[2], hi[3]);
        nfb[i] = o;
    } else if (i < NNF + 8192) {
        int j = i - NNF;
        int m = j >> 11;
        int t = j & 2047;
        const float* W = (m == 0) ? Wn0 : (m == 1) ? Ws0 : (m == 2) ? Wn1 : Ws1;
        f32x4 lo = ((const f32x4*)W)[2 * t];
        f32x4 hi = ((const f32x4*)W)[2 * t + 1];
        u32x4 o;
        o.x = pack_bf2(lo[0], lo[1]);
        o.y = pack_bf2(lo[2], lo[3]);
        o.z = pack_bf2(hi[0], hi[1]);
        o.w = pack_bf2(hi[2], hi[3]);
        *(u32x4*)(wbf + (size_t)m * 8192 + 4 * t) = o;
    } else {
        int e = i - NNF - 8192;
        if (e < N_EDGES) atomicAdd(&deg[dst[e]], 1);
    }
}

// ---------------- CSR build ----------------

// scan1 also emits the iso-node list (deg==0)
__global__ void k_scan1(const int* __restrict__ deg, int* __restrict__ offs,
                        int* __restrict__ part, int* __restrict__ isolist,
                        int* __restrict__ niso) {
    __shared__ int sm[256];
    int t = threadIdx.x;
    int i = blockIdx.x * 256 + t;
    int v = (i < N_NODES) ? deg[i] : 0;
    int orig = v;
    if (i < N_NODES && orig == 0) {
        int p = atomicAdd(niso, 1);
        isolist[p] = i;
    }
    sm[t] = v;
    __syncthreads();
    for (int off = 1; off < 256; off <<= 1) {
        int x = (t >= off) ? sm[t - off] : 0;
        __syncthreads();
        sm[t] += x;
        __syncthreads();
    }
    if (i < N_NODES) offs[i] = sm[t] - orig;  // exclusive within block
    if (t == 255) part[blockIdx.x] = sm[t];   // block total
}

__global__ void k_scan2(int* __restrict__ part, int nb) {
    __shared__ int sm[256];
    int t = threadIdx.x;
    int v = (t < nb) ? part[t] : 0;
    int orig = v;
    sm[t] = v;
    __syncthreads();
    for (int off = 1; off < 256; off <<= 1) {
        int x = (t >= off) ? sm[t - off] : 0;
        __syncthreads();
        sm[t] += x;
        __syncthreads();
    }
    if (t < nb) part[t] = sm[t] - orig;  // exclusive block offsets
}

// scan3 also initializes cur = final offs, so k_fill needs only one atomic
__global__ void k_scan3(int* __restrict__ offs, const int* __restrict__ part,
                        int* __restrict__ cur) {
    int i = blockIdx.x * 256 + threadIdx.x;
    if (i < N_NODES) {
        int v = offs[i] + part[blockIdx.x];
        offs[i] = v;
        cur[i] = v;
    }
}

__global__ void k_fill(const int* __restrict__ src, const int* __restrict__ dst,
                       int* __restrict__ cur, int2* __restrict__ csr) {
    int e = blockIdx.x * 256 + threadIdx.x;
    if (e < N_EDGES) {
        int p = atomicAdd(&cur[dst[e]], 1);
        csr[p] = make_int2(src[e], e);  // (src node, edge id)
    }
}

// ---------------- layer-1 aggregation: 2 edge slots, occupancy-forced ----------------
// half-wave (32 lanes) per edge; lane covers element group [4c, 4c+4).
// efsum[n] = sum edge_feats (bf16-packed, reused by layer 2)
// pre[n]   = (sum nf_bf16[src] + efsum[n]) / max(deg,1)   (bf16-packed)
// launch_bounds(256,8): cap VGPR at 64 -> 8 waves/SIMD for gather-latency TLP.

__global__ void __launch_bounds__(256, 8)
k_agg_ef(const unsigned int* __restrict__ nfb,  // bf16 [N*64]
         const f32x4* __restrict__ ef,          // fp32 [E*32]
         const int2* __restrict__ csr,
         const int* __restrict__ offs, const int* __restrict__ deg,
         unsigned int* __restrict__ efsum,
         unsigned int* __restrict__ pre) {
    int node = blockIdx.x * 4 + (threadIdx.x >> 6);
    if (node >= N_NODES) return;
    int lane = threadIdx.x & 63;
    int half = lane >> 5;  // which edge of the pair this lane handles
    int c = lane & 31;     // element group [4c, 4c+4)
    int start = offs[node];
    int cnt = deg[node];
    f32x4 ae = {0.f, 0.f, 0.f, 0.f};
    f32x4 ah = {0.f, 0.f, 0.f, 0.f};
#pragma unroll 2
    for (int k = half; k < cnt; k += 2) {
        int2 se = csr[start + k];
        // nt: the 410MB ef stream is read-once; keep it from evicting nfb/csr in L2/L3
        f32x4 ev = __builtin_nontemporal_load(&ef[(size_t)se.y * 32 + c]);
        u32x2 hv = *(const u32x2*)(nfb + (size_t)se.x * D2 + 2 * c);
        ae[0] += ev[0];
        ae[1] += ev[1];
        ae[2] += ev[2];
        ae[3] += ev[3];
        ah[0] += bf_lo(hv.x);
        ah[1] += bf_hi(hv.x);
        ah[2] += bf_lo(hv.y);
        ah[3] += bf_hi(hv.y);
    }
    // combine the two halves
#pragma unroll
    for (int i = 0; i < 4; ++i) {
        ae[i] += __shfl_xor(ae[i], 32);
        ah[i] += __shfl_xor(ah[i], 32);
    }
    float inv = 1.0f / fmaxf((float)cnt, 1.0f);
    if (half == 0) {
        u32x2 eo;
        eo.x = pack_bf2(ae[0], ae[1]);
        eo.y = pack_bf2(ae[2], ae[3]);
        *(u32x2*)(efsum + (size_t)node * D2 + 2 * c) = eo;
    } else {
        u32x2 po;
        po.x = pack_bf2((ah[0] + ae[0]) * inv, (ah[1] + ae[1]) * inv);
        po.y = pack_bf2((ah[2] + ae[2]) * inv, (ah[3] + ae[3]) * inv);
        *(u32x2*)(pre + (size_t)node * D2 + 2 * c) = po;
    }
}

// ---------------- layer-2 aggregation: 4 edge slots, occupancy-forced ----------------
// quarter-wave (16 lanes) per edge; lane covers element group [8g, 8g+8).

__global__ void __launch_bounds__(256, 8)
k_agg2(const unsigned int* __restrict__ h,  // h1 bf16 [N*64]
       const int2* __restrict__ csr,
       const int* __restrict__ offs, const int* __restrict__ deg,
       const unsigned int* __restrict__ efsum,
       unsigned int* __restrict__ pre) {
    int node = blockIdx.x * 4 + (threadIdx.x >> 6);
    if (node >= N_NODES) return;
    int lane = threadIdx.x & 63;
    int q = lane >> 4;  // which edge of the quad
    int g = lane & 15;  // element group [8g, 8g+8)
    int start = offs[node];
    int cnt = deg[node];
    float a[8] = {0.f, 0.f, 0.f, 0.f, 0.f, 0.f, 0.f, 0.f};
#pragma unroll 4
    for (int k = q; k < cnt; k += 4) {
        int2 se = csr[start + k];
        u32x4 hv = *(const u32x4*)(h + (size_t)se.x * D2 + 4 * g);
        a[0] += bf_lo(hv.x);
        a[1] += bf_hi(hv.x);
        a[2] += bf_lo(hv.y);
        a[3] += bf_hi(hv.y);
        a[4] += bf_lo(hv.z);
        a[5] += bf_hi(hv.z);
        a[6] += bf_lo(hv.w);
        a[7] += bf_hi(hv.w);
    }
    // combine the four quarters
#pragma unroll
    for (int i = 0; i < 8; ++i) {
        a[i] += __shfl_xor(a[i], 16);
        a[i] += __shfl_xor(a[i], 32);
    }
    if (q == 0) {
        u32x4 es = *(const u32x4*)(efsum + (size_t)node * D2 + 4 * g);
        float inv = 1.0f / fmaxf((float)cnt, 1.0f);
        float r0 = (a[0] + bf_lo(es.x)) * inv;
        float r1 = (a[1] + bf_hi(es.x)) * inv;
        float r2 = (a[2] + bf_lo(es.y)) * inv;
        float r3 = (a[3] + bf_hi(es.y)) * inv;
        float r4 = (a[4] + bf_lo(es.z)) * inv;
        float r5 = (a[5] + bf_hi(es.z)) * inv;
        float r6 = (a[6] + bf_lo(es.w)) * inv;
        float r7 = (a[7] + bf_hi(es.w)) * inv;
        u32x4 o;
        o.x = pack_bf2(r0, r1);
        o.y = pack_bf2(r2, r3);
        o.z = pack_bf2(r4, r5);
        o.w = pack_bf2(r6, r7);
        *(u32x4*)(pre + (size_t)node * D2 + 4 * g) = o;
    }
}

// ---------------- fused GEMM: out = leaky(pre@Wn^T + h@Ws^T) ----------------
// NT GEMM, M=50000, N=128, K=256 ([pre|h] @ [Wn|Ws]^T). All operands bf16.
// 32 rows per wave (2 m-tiles) — measured-best config.

template <int OUT_F32>
__global__ void k_gemm(const unsigned short* __restrict__ A1,  // pre [M,128] bf16
                       const unsigned short* __restrict__ A2,  // h   [M,128] bf16
                       const unsigned short* __restrict__ W1,  // Wn bf16
                       const unsigned short* __restrict__ W2,  // Ws bf16
                       void* __restrict__ outv) {
    int wave = threadIdx.x >> 6;
    int lane = threadIdx.x & 63;
    int quad = lane >> 4;
    int r16 = lane & 15;
    int m0 = (blockIdx.x * 4 + wave) * 32;  // 32 rows per wave (2 m-tiles)

    f32x4 acc[2][8];
#pragma unroll
    for (int mt = 0; mt < 2; ++mt)
#pragma unroll
        for (int nt = 0; nt < 8; ++nt) acc[mt][nt] = (f32x4){0.f, 0.f, 0.f, 0.f};

    int rowA0 = min(m0 + r16, N_NODES - 1);
    int rowA1 = min(m0 + 16 + r16, N_NODES - 1);

#pragma unroll
    for (int ks = 0; ks < 8; ++ks) {
        int koff = (ks & 3) * 32 + quad * 8;  // lane's 8 contiguous k
        const unsigned short* Asrc = (ks < 4) ? A1 : A2;
        bf16x8 a0 = *(const bf16x8*)(Asrc + (size_t)rowA0 * D + koff);
        bf16x8 a1 = *(const bf16x8*)(Asrc + (size_t)rowA1 * D + koff);
        const unsigned short* Wsrc = (ks < 4) ? W1 : W2;
#pragma unroll
        for (int nt = 0; nt < 8; ++nt) {
            bf16x8 b = *(const bf16x8*)(Wsrc + (size_t)(nt * 16 + r16) * D + koff);
            acc[0][nt] = __builtin_amdgcn_mfma_f32_16x16x32_bf16(a0, b, acc[0][nt], 0, 0, 0);
            acc[1][nt] = __builtin_amdgcn_mfma_f32_16x16x32_bf16(a1, b, acc[1][nt], 0, 0, 0);
        }
    }

    // C/D layout: col = lane&15, row = quad*4 + reg (m89/m91-verified)
#pragma unroll
    for (int mt = 0; mt < 2; ++mt) {
#pragma unroll
        for (int r = 0; r < 4; ++r) {
            int row = m0 + mt * 16 + quad * 4 + r;
            if (row < N_NODES) {
#pragma unroll
                for (int nt = 0; nt < 8; ++nt) {
                    float x = acc[mt][nt][r];
                    x = (x >= 0.f) ? x : x * SLOPE;
                    if (OUT_F32)
                        __builtin_nontemporal_store(
                            x, &((float*)outv)[(size_t)row * D + nt * 16 + r16]);
                    else
                        ((unsigned short*)outv)[(size_t)row * D + nt * 16 + r16] = f2bf(x);
                }
            }
        }
    }
}

// iso nodes (deg==0): out[n] = leaky(h[n] @ Wi^T), overwriting the GEMM value.
// Driven by the iso list; expected empty, so these are ~free.

__global__ void k_fixup1(const unsigned int* __restrict__ nfb,  // node_feats bf16
                         const float* __restrict__ Wi,          // fp32
                         const int* __restrict__ isolist, const int* __restrict__ niso,
                         unsigned short* __restrict__ out) {  // h1 bf16
    int w = blockIdx.x * 4 + (threadIdx.x >> 6);
    int lane = threadIdx.x & 63;
    int n = *niso;
    for (int t = w; t < n; t += gridDim.x * 4) {
        int node = isolist[t];
        const unsigned int* hrow = nfb + (size_t)node * D2;
        float a0 = 0.f, a1 = 0.f;
        for (int ku = 0; ku < D2; ++ku) {
            unsigned int v = hrow[ku];
            float h0 = bf_lo(v), h1 = bf_hi(v);
            a0 += h0 * Wi[(size_t)lane * D + 2 * ku] + h1 * Wi[(size_t)lane * D + 2 * ku + 1];
            a1 += h0 * Wi[(size_t)(lane + 64) * D + 2 * ku] +
                  h1 * Wi[(size_t)(lane + 64) * D + 2 * ku + 1];
        }
        a0 = (a0 >= 0.f) ? a0 : a0 * SLOPE;
        a1 = (a1 >= 0.f) ? a1 : a1 * SLOPE;
        out[(size_t)node * D + lane] = f2bf(a0);
        out[(size_t)node * D + lane + 64] = f2bf(a1);
    }
}

__global__ void k_fixup2(const unsigned short* __restrict__ h,  // h1 bf16
                         const float* __restrict__ Wi,          // fp32
                         const int* __restrict__ isolist, const int* __restrict__ niso,
                         float* __restrict__ out) {  // d_out fp32
    int w = blockIdx.x * 4 + (threadIdx.x >> 6);
    int lane = threadIdx.x & 63;
    int n = *niso;
    for (int t = w; t < n; t += gridDim.x * 4) {
        int node = isolist[t];
        const unsigned short* hrow = h + (size_t)node * D;
        float a0 = 0.f, a1 = 0.f;
        for (int k = 0; k < D; ++k) {
            float hk = __uint_as_float(((unsigned int)hrow[k]) << 16);
            a0 += hk * Wi[(size_t)lane * D + k];
            a1 += hk * Wi[(size_t)(lane + 64) * D + k];
        }
        a0 = (a0 >= 0.f) ? a0 : a0 * SLOPE;
        a1 = (a1 >= 0.f) ? a1 : a1 * SLOPE;
        out[(size_t)node * D + lane] = a0;
        out[(size_t)node * D + lane + 64] = a1;
    }
}

// ---------------- launch ----------------

extern "C" void kernel_launch(void* const* d_in, const int* in_sizes, int n_in,
                              void* d_out, int out_size, void* d_ws, size_t ws_size,
                              hipStream_t stream) {
    const float* node_feats = (const float*)d_in[0];
    const float* edge_feats = (const float*)d_in[1];
    const int* src = (const int*)d_in[2];
    const int* dst = (const int*)d_in[3];
    const float* Wn0 = (const float*)d_in[4];
    const float* Ws0 = (const float*)d_in[5];
    const float* Wi0 = (const float*)d_in[6];
    const float* Wn1 = (const float*)d_in[7];
    const float* Ws1 = (const float*)d_in[8];
    const float* Wi1 = (const float*)d_in[9];

    char* ws = (char*)d_ws;
    size_t o = 0;
    auto alloc = [&](size_t bytes) -> char* {
        char* p = ws + o;
        o += (bytes + 255) & ~size_t(255);
        return p;
    };
    int* deg = (int*)alloc((size_t)N_NODES * 4);  // zeroed
    int* niso = (int*)alloc(256);                 // zeroed (contiguous with deg)
    int* cur = (int*)alloc((size_t)N_NODES * 4);  // init by k_scan3
    int* offs = (int*)alloc((size_t)N_NODES * 4);
    int* part = (int*)alloc(1024);
    int* isolist = (int*)alloc((size_t)N_NODES * 4);
    int2* csr = (int2*)alloc((size_t)N_EDGES * 8);                        //  6.4 MB
    unsigned int* efsum = (unsigned int*)alloc((size_t)N_NODES * D * 2);  // 12.8 MB
    unsigned int* pre = (unsigned int*)alloc((size_t)N_NODES * D * 2);    // 12.8 MB
    unsigned int* h1 = (unsigned int*)alloc((size_t)N_NODES * D * 2);     // 12.8 MB
    unsigned int* nfb = (unsigned int*)alloc((size_t)N_NODES * D * 2);    // 12.8 MB
    unsigned int* wbf = (unsigned int*)alloc(4 * 8192 * 4);               // 128 KB

    // zero deg + niso (contiguous allocations)
    hipMemsetAsync(deg, 0, (((size_t)N_NODES * 4 + 255) & ~size_t(255)) + 256, stream);

    int nbl = (N_NODES + 255) / 256;  // 196
    int nwb = (N_NODES + 3) / 4;      // 12500 (4 waves/block, wave-per-node)
    int gbl = (N_NODES + 127) / 128;  // 391 (128 rows/block, 32/wave)
    int ccbl = (N_NODES * D / 8 + 8192 + N_EDGES + 255) / 256;  // 6282
    int ebl = (N_EDGES + 255) / 256;  // 3125

    k_cvt_count<<<ccbl, 256, 0, stream>>>((const f32x4*)node_feats, Wn0, Ws0, Wn1, Ws1, dst,
                                          (u32x4*)nfb, wbf, deg);
    k_scan1<<<nbl, 256, 0, stream>>>(deg, offs, part, isolist, niso);
    k_scan2<<<1, 256, 0, stream>>>(part, nbl);
    k_scan3<<<nbl, 256, 0, stream>>>(offs, part, cur);
    k_fill<<<ebl, 256, 0, stream>>>(src, dst, cur, csr);

    const unsigned short* Wn0b = (const unsigned short*)(wbf + 0 * 8192);
    const unsigned short* Ws0b = (const unsigned short*)(wbf + 1 * 8192);
    const unsigned short* Wn1b = (const unsigned short*)(wbf + 2 * 8192);
    const unsigned short* Ws1b = (const unsigned short*)(wbf + 3 * 8192);

    // layer 1: nfb (bf16) -> h1 (bf16); also builds efsum (bf16)
    k_agg_ef<<<nwb, 256, 0, stream>>>(nfb, (const f32x4*)edge_feats, csr, offs, deg, efsum, pre);
    k_gemm<0><<<gbl, 256, 0, stream>>>((const unsigned short*)pre, (const unsigned short*)nfb,
                                       Wn0b, Ws0b, (void*)h1);
    k_fixup1<<<32, 256, 0, stream>>>(nfb, Wi0, isolist, niso, (unsigned short*)h1);

    // layer 2: h1 (bf16) -> d_out (fp32)
    k_agg2<<<nwb, 256, 0, stream>>>(h1, csr, offs, deg, efsum, pre);
    k_gemm<1><<<gbl, 256, 0, stream>>>((const unsigned short*)pre, (const unsigned short*)h1,
                                       Wn1b, Ws1b, d_out);
    k_fixup2<<<32, 256, 0, stream>>>((const unsigned short*)h1, Wi1, isolist, niso, (float*)d_out);
}